// Round 5
// baseline (227.869 us; speedup 1.0000x reference)
//
#include <hip/hip_runtime.h>
#include <math.h>

#define BATCH 8
#define SEQ 4096
#define DIMSZ 384
#define HEADS 6
#define DH 64
#define MTOT (BATCH * SEQ) /* 32768 */
#define KD 384

typedef short short8 __attribute__((ext_vector_type(8)));
typedef float floatx4 __attribute__((ext_vector_type(4)));
typedef unsigned short ushort4v __attribute__((ext_vector_type(4)));
typedef unsigned short ushort8v __attribute__((ext_vector_type(8)));
typedef unsigned int uint2v __attribute__((ext_vector_type(2)));
typedef unsigned int uint4v __attribute__((ext_vector_type(4)));

__device__ __forceinline__ float elu1(float x) { return x > 0.f ? x + 1.f : __expf(x); }

__device__ __forceinline__ unsigned short f2b(float f) {
    unsigned int u = __float_as_uint(f);
    u = (u + 0x7fffu + ((u >> 16) & 1u)) >> 16;
    return (unsigned short)u;
}
__device__ __forceinline__ float b2f(unsigned short u) {
    return __uint_as_float(((unsigned int)u) << 16);
}
// packed fp32x2 -> bf16x2 via v_cvt_pk_bf16_f32 (RNE == manual f2b rounding).
__device__ __forceinline__ unsigned int f2b2(float lo, float hi) {
    unsigned int r;
    asm("v_cvt_pk_bf16_f32 %0, %1, %2" : "=v"(r) : "v"(lo), "v"(hi));
    return r;
}

__device__ __forceinline__ void gl16(const void* g, void* l) {
    __builtin_amdgcn_global_load_lds((const __attribute__((address_space(1))) unsigned int*)g,
                                     (__attribute__((address_space(3))) unsigned int*)l, 16, 0, 0);
}

// Counted pre-MFMA barrier: wait B-gl16 (older) into LDS + ds_writes, leave the
// N youngest VMEM ops (A prefetch) in flight. Raw s_barrier (no compiler drain).
#define BARRIER_EXEMPT8()                                              \
    do {                                                               \
        asm volatile("s_waitcnt vmcnt(8) lgkmcnt(0)" ::: "memory");    \
        __builtin_amdgcn_s_barrier();                                  \
        __builtin_amdgcn_sched_barrier(0);                             \
    } while (0)
#define BARRIER_EXEMPT4()                                              \
    do {                                                               \
        asm volatile("s_waitcnt vmcnt(4) lgkmcnt(0)" ::: "memory");    \
        __builtin_amdgcn_s_barrier();                                  \
        __builtin_amdgcn_sched_barrier(0);                             \
    } while (0)
#define BARRIER_DRAIN()                                                \
    do {                                                               \
        asm volatile("s_waitcnt vmcnt(0) lgkmcnt(0)" ::: "memory");    \
        __builtin_amdgcn_s_barrier();                                  \
        __builtin_amdgcn_sched_barrier(0);                             \
    } while (0)

// ---------------------------------------------------------------------------
// All three weights: W[384][N] fp32 -> WT[N][384] bf16 (transpose + convert).
// ---------------------------------------------------------------------------
__global__ __launch_bounds__(256) void conv_wt3(const float* __restrict__ Wq,
                                                const float* __restrict__ Wkv,
                                                const float* __restrict__ Wout,
                                                unsigned short* __restrict__ WqT,
                                                unsigned short* __restrict__ WkvT,
                                                unsigned short* __restrict__ WoutT) {
    __shared__ float tile[32][33];
    int bx = blockIdx.x;
    const float* W;
    unsigned short* WT;
    int N;
    if (bx < 12) { W = Wq; WT = WqT; N = DIMSZ; }
    else if (bx < 36) { W = Wkv; WT = WkvT; N = 2 * DIMSZ; bx -= 12; }
    else { W = Wout; WT = WoutT; N = DIMSZ; bx -= 36; }
    const int n0 = bx * 32, k0 = blockIdx.y * 32;
    const int tx = threadIdx.x & 31, ty = threadIdx.x >> 5;  // 32 x 8
#pragma unroll
    for (int i = 0; i < 32; i += 8) tile[ty + i][tx] = W[(size_t)(k0 + ty + i) * N + n0 + tx];
    __syncthreads();
#pragma unroll
    for (int i = 0; i < 32; i += 8)
        WT[(size_t)(n0 + ty + i) * KD + k0 + tx] = f2b(tile[tx][ty + i]);
}

// ---------------------------------------------------------------------------
// Fused kv-projection + kv-state partial. A = x_kv fp32, reg-staged with
// 1-DEEP PREFETCH: next K-step's 8 float4 loads issue before the MFMA phase;
// the pre-MFMA barrier is a counted vmcnt(8) (exempts them) instead of the
// compiler's vmcnt(0) drain (R4: sync A-path left MfmaUtil at 15%, 70% idle).
// Loop-top __syncthreads drains them exactly where they're consumed.
// launch_bounds(256,3): +32 prefetch regs; forcing <=128 would spill.
// ---------------------------------------------------------------------------
__global__ __launch_bounds__(256, 3) void gemm_kv(const float* __restrict__ A,
                                                  const unsigned short* __restrict__ WkvT,
                                                  float* __restrict__ pkv,
                                                  float* __restrict__ pks) {
    __shared__ __align__(16) unsigned short buf[17408];  // As|Bs, reused as epi tile
    __shared__ float ksLDS[128];
    unsigned short* As = buf;
    unsigned short* Bs = buf + 8192;
    const int tid = threadIdx.x;
    const int lane = tid & 63, wave = tid >> 6;
    const int l15 = lane & 15, qd = lane >> 4;
    const int fid = blockIdx.x;
    const int xcd = fid & 7;
    const int s = fid >> 3;          // 0..191
    const int h = s % HEADS;
    const int rtl = s / HEADS;       // 0..31
    const int row0 = (xcd * 32 + rtl) * 128;
    const int pidx = (xcd * HEADS + h) * 32 + rtl;
    const int wm = (wave & 1) * 64, wn = (wave >> 1) * 64;

    const float* Ab = A + (size_t)row0 * KD;
    const unsigned short* Bb = WkvT + (size_t)(h * DH) * KD;  // k rows; v rows at +320*KD bias
    const int srow = tid >> 3;
    const int scol = (((tid & 7) ^ (srow & 7)) * 8);

    floatx4 zero = {0.f, 0.f, 0.f, 0.f};
    floatx4 acc[4][4];
#pragma unroll
    for (int i = 0; i < 4; ++i)
#pragma unroll
        for (int j = 0; j < 4; ++j) acc[i][j] = zero;

    const int sw = l15 & 7;
    float4 g0[4], g1[4];
#pragma unroll
    for (int i = 0; i < 4; ++i) {  // A(0) prefetch
        const float* src = Ab + (size_t)(i * 32 + srow) * KD + scol;
        g0[i] = *(const float4*)src;
        g1[i] = *(const float4*)(src + 4);
    }
#pragma unroll
    for (int kk = 0; kk < KD; kk += 64) {
        __syncthreads();  // prev MFMA reads done; drains A(kk) right before use
#pragma unroll
        for (int i = 0; i < 4; ++i)  // B: bf16 weights via global_load_lds
            gl16(Bb + (size_t)(i * 32 + srow + (i >= 2 ? 320 : 0)) * KD + kk + scol,
                 Bs + i * 2048 + wave * 512);
#pragma unroll
        for (int i = 0; i < 4; ++i) {  // cvt A(kk) -> swizzled LDS
            uint4v u;
            u[0] = f2b2(g0[i].x, g0[i].y);
            u[1] = f2b2(g0[i].z, g0[i].w);
            u[2] = f2b2(g1[i].x, g1[i].y);
            u[3] = f2b2(g1[i].z, g1[i].w);
            *(uint4v*)&As[i * 2048 + tid * 8] = u;
        }
        if (kk + 64 < KD) {
#pragma unroll
            for (int i = 0; i < 4; ++i) {  // A(kk+64) prefetch: rides through barrier
                const float* src = Ab + (size_t)(i * 32 + srow) * KD + kk + 64 + scol;
                g0[i] = *(const float4*)src;
                g1[i] = *(const float4*)(src + 4);
            }
            BARRIER_EXEMPT8();
        } else {
            BARRIER_DRAIN();
        }
#pragma unroll
        for (int t = 0; t < 2; ++t) {
            const int chnk = ((t * 4 + qd) ^ sw) * 8;
            short8 af[4], bfr[4];
#pragma unroll
            for (int mi = 0; mi < 4; ++mi)
                af[mi] = *(const short8*)&As[(wm + mi * 16 + l15) * 64 + chnk];
#pragma unroll
            for (int ni = 0; ni < 4; ++ni)
                bfr[ni] = *(const short8*)&Bs[(wn + ni * 16 + l15) * 64 + chnk];
#pragma unroll
            for (int mi = 0; mi < 4; ++mi)
#pragma unroll
                for (int ni = 0; ni < 4; ++ni)
                    acc[mi][ni] = __builtin_amdgcn_mfma_f32_16x16x32_bf16(af[mi], bfr[ni],
                                                                          acc[mi][ni], 0, 0, 0);
        }
    }

    __syncthreads();  // K-loop LDS reads done before buf reuse
    // transposed bf16 tile buf[c][n] with ksum fused (k-half waves: wn==0)
    const bool kw = (wn == 0);
    float ksp[4] = {};
#pragma unroll
    for (int mi = 0; mi < 4; ++mi)
#pragma unroll
        for (int ni = 0; ni < 4; ++ni) {
            const int rb = wm + mi * 16 + qd * 4;
            const int cl = wn + ni * 16 + l15;
            float v0 = acc[mi][ni][0], v1 = acc[mi][ni][1];
            float v2 = acc[mi][ni][2], v3 = acc[mi][ni][3];
            if (kw) {
                v0 = elu1(v0); v1 = elu1(v1); v2 = elu1(v2); v3 = elu1(v3);
                ksp[ni] += (v0 + v1) + (v2 + v3);
            }
            uint2v o;
            o[0] = f2b2(v0, v1);
            o[1] = f2b2(v2, v3);
            *(uint2v*)&buf[cl * 136 + rb] = o;
        }
    if (kw) {
#pragma unroll
        for (int ni = 0; ni < 4; ++ni) {
            float v = ksp[ni];
            v += __shfl_xor(v, 16);
            v += __shfl_xor(v, 32);
            if (lane < 16) ksLDS[wave * 64 + ni * 16 + lane] = v;
        }
    }
    __syncthreads();
    // kv partial: wave w owns d-strip [w*16, w*16+16); reduce over n=128 (4 ksteps)
    floatx4 kva[4];
#pragma unroll
    for (int j = 0; j < 4; ++j) kva[j] = zero;
#pragma unroll
    for (int nk = 0; nk < 4; ++nk) {
        short8 afk = *(const short8*)&buf[(wave * 16 + l15) * 136 + nk * 32 + qd * 8];
#pragma unroll
        for (int nj = 0; nj < 4; ++nj) {
            short8 bfv = *(const short8*)&buf[(64 + nj * 16 + l15) * 136 + nk * 32 + qd * 8];
            kva[nj] = __builtin_amdgcn_mfma_f32_16x16x32_bf16(afk, bfv, kva[nj], 0, 0, 0);
        }
    }
    // plain stores (not nt): keep partials in L2/L3 for kv_reduce
    float* P = pkv + (size_t)pidx * 4096;
#pragma unroll
    for (int nj = 0; nj < 4; ++nj)
#pragma unroll
        for (int r = 0; r < 4; ++r)
            P[(wave * 16 + qd * 4 + r) * 64 + nj * 16 + l15] = kva[nj][r];
    if (tid < 64) pks[pidx * 64 + tid] = ksLDS[tid] + ksLDS[64 + tid];
}

// ---------------------------------------------------------------------------
// reduce 32 partials per bh -> kv bf16 TRANSPOSED [bh][m][64 d], ksum fp32.
// ---------------------------------------------------------------------------
__global__ __launch_bounds__(256) void kv_reduce(const float* __restrict__ pkv,
                                                 const float* __restrict__ pks,
                                                 unsigned short* __restrict__ kv_bf,
                                                 float* __restrict__ ksum_g) {
    const int bh = blockIdx.x >> 2, dc = blockIdx.x & 3;
    const int tid = threadIdx.x;
    unsigned short* kb = kv_bf + (size_t)bh * 4096;
    const int i0 = dc * 1024 + tid * 4;
    float4 sum = {0.f, 0.f, 0.f, 0.f};
#pragma unroll
    for (int c = 0; c < 32; ++c) {
        float4 p = *(const float4*)&pkv[(size_t)(bh * 32 + c) * 4096 + i0];
        sum.x += p.x; sum.y += p.y; sum.z += p.z; sum.w += p.w;
    }
    const int d = i0 >> 6, m = i0 & 63;  // i0 d-major; 4 consecutive m, same d
    kb[(m + 0) * 64 + d] = f2b(sum.x);
    kb[(m + 1) * 64 + d] = f2b(sum.y);
    kb[(m + 2) * 64 + d] = f2b(sum.z);
    kb[(m + 3) * 64 + d] = f2b(sum.w);
    if (dc == 0 && tid < 64) {
        float s = 0.f;
#pragma unroll
        for (int c = 0; c < 32; ++c) s += pks[(bh * 32 + c) * 64 + tid];
        ksum_g[bh * 64 + tid] = s;
    }
}

// ---------------------------------------------------------------------------
// Fused q-projection + attention (swapped C = q^T). Same prefetch + counted
// barrier as gemm_kv. kv B-fragments direct from global (L2-resident).
// ---------------------------------------------------------------------------
__global__ __launch_bounds__(256, 3) void gemm_q_attn(const float* __restrict__ A,
                                                      const unsigned short* __restrict__ WqT,
                                                      const unsigned short* __restrict__ kv_bf,
                                                      const float* __restrict__ ksum_g,
                                                      unsigned short* __restrict__ attn) {
    __shared__ __align__(16) unsigned short buf[17408];  // As|Bs, reused as q tile
    __shared__ float ksh[128];
    __shared__ float zsh[256];                           // [2][128]
    unsigned short* As = buf;
    unsigned short* Bs = buf + 8192;
    const int tid = threadIdx.x;
    const int lane = tid & 63, wave = tid >> 6;
    const int l15 = lane & 15, qd = lane >> 4;
    const int fid = blockIdx.x;
    const int xcd = fid & 7;
    const int s = fid >> 3;          // 0..95
    const int ct = s % 3;
    const int rtl = s / 3;
    const int row0 = (xcd * 32 + rtl) * 128;
    const int col0 = ct * 128;
    const int bh0 = xcd * HEADS + ct * 2;
    const int wd = (wave & 1) * 64, wn2 = (wave >> 1) * 64;

    if (tid < 128) ksh[tid] = ksum_g[bh0 * 64 + tid];

    const float* Ab = A + (size_t)row0 * KD;
    const unsigned short* Bb = WqT + (size_t)col0 * KD;
    const int srow = tid >> 3;
    const int scol = (((tid & 7) ^ (srow & 7)) * 8);

    floatx4 zero = {0.f, 0.f, 0.f, 0.f};
    floatx4 acc[4][4];
#pragma unroll
    for (int i = 0; i < 4; ++i)
#pragma unroll
        for (int j = 0; j < 4; ++j) acc[i][j] = zero;

    const int sw = l15 & 7;
    float4 g0[4], g1[4];
#pragma unroll
    for (int i = 0; i < 4; ++i) {  // A(0) prefetch
        const float* src = Ab + (size_t)(i * 32 + srow) * KD + scol;
        g0[i] = *(const float4*)src;
        g1[i] = *(const float4*)(src + 4);
    }
#pragma unroll
    for (int kk = 0; kk < KD; kk += 64) {
        __syncthreads();
#pragma unroll
        for (int i = 0; i < 4; ++i)
            gl16(Bb + (size_t)(i * 32 + srow) * KD + kk + scol, Bs + i * 2048 + wave * 512);
#pragma unroll
        for (int i = 0; i < 4; ++i) {
            uint4v u;
            u[0] = f2b2(g0[i].x, g0[i].y);
            u[1] = f2b2(g0[i].z, g0[i].w);
            u[2] = f2b2(g1[i].x, g1[i].y);
            u[3] = f2b2(g1[i].z, g1[i].w);
            *(uint4v*)&As[i * 2048 + tid * 8] = u;
        }
        if (kk + 64 < KD) {
#pragma unroll
            for (int i = 0; i < 4; ++i) {
                const float* src = Ab + (size_t)(i * 32 + srow) * KD + kk + 64 + scol;
                g0[i] = *(const float4*)src;
                g1[i] = *(const float4*)(src + 4);
            }
            BARRIER_EXEMPT8();
        } else {
            BARRIER_DRAIN();
        }
#pragma unroll
        for (int t = 0; t < 2; ++t) {
            const int chnk = ((t * 4 + qd) ^ sw) * 8;
            short8 wf[4], xf[4];
#pragma unroll
            for (int di = 0; di < 4; ++di)
                wf[di] = *(const short8*)&Bs[(wd + di * 16 + l15) * 64 + chnk];
#pragma unroll
            for (int nj = 0; nj < 4; ++nj)
                xf[nj] = *(const short8*)&As[(wn2 + nj * 16 + l15) * 64 + chnk];
#pragma unroll
            for (int di = 0; di < 4; ++di)
#pragma unroll
                for (int nj = 0; nj < 4; ++nj)  // swapped: C[d][n]
                    acc[di][nj] = __builtin_amdgcn_mfma_f32_16x16x32_bf16(wf[di], xf[nj],
                                                                          acc[di][nj], 0, 0, 0);
        }
    }

    // elu + z partials: this wave's d-range = one full head (wd selects head)
    float zp[4] = {};
#pragma unroll
    for (int di = 0; di < 4; ++di)
#pragma unroll
        for (int r = 0; r < 4; ++r) {
            const float ks = ksh[wd + di * 16 + qd * 4 + r];
#pragma unroll
            for (int nj = 0; nj < 4; ++nj) {
                const float q = elu1(acc[di][nj][r]);
                acc[di][nj][r] = q;
                zp[nj] += q * ks;
            }
        }
#pragma unroll
    for (int nj = 0; nj < 4; ++nj) {
        float v = zp[nj];
        v += __shfl_xor(v, 16);
        v += __shfl_xor(v, 32);
        zp[nj] = 1.f / (v + 1e-6f);
    }
    __syncthreads();  // K-loop LDS reads done before buf reuse
    if (lane < 16) {
#pragma unroll
        for (int nj = 0; nj < 4; ++nj) zsh[(wave & 1) * 128 + wn2 + nj * 16 + lane] = zp[nj];
    }
    // transposed write -> q ROW-MAJOR in LDS: buf[n][d], stride 136
#pragma unroll
    for (int di = 0; di < 4; ++di)
#pragma unroll
        for (int nj = 0; nj < 4; ++nj) {
            const int rb = wd + di * 16 + qd * 4;    // d
            const int cl = wn2 + nj * 16 + l15;      // n
            uint2v o;
            o[0] = f2b2(acc[di][nj][0], acc[di][nj][1]);
            o[1] = f2b2(acc[di][nj][2], acc[di][nj][3]);
            *(uint2v*)&buf[cl * 136 + rb] = o;
        }
    __syncthreads();
    // attn quadrant: n in [wn2,wn2+64), head hh = wave&1, K = 64 d (2 ksteps)
    const int hh = wave & 1;
    const unsigned short* kvB = kv_bf + (size_t)(bh0 + hh) * 4096;
    floatx4 acc2[4][4];
#pragma unroll
    for (int i = 0; i < 4; ++i)
#pragma unroll
        for (int j = 0; j < 4; ++j) acc2[i][j] = zero;
#pragma unroll
    for (int t = 0; t < 2; ++t) {
        short8 bf2[4];
#pragma unroll
        for (int bj = 0; bj < 4; ++bj)
            bf2[bj] = *(const short8*)&kvB[(bj * 16 + l15) * 64 + t * 32 + qd * 8];
#pragma unroll
        for (int ai = 0; ai < 4; ++ai) {
            short8 af =
                *(const short8*)&buf[(wn2 + ai * 16 + l15) * 136 + hh * 64 + t * 32 + qd * 8];
#pragma unroll
            for (int bj = 0; bj < 4; ++bj)
                acc2[ai][bj] =
                    __builtin_amdgcn_mfma_f32_16x16x32_bf16(af, bf2[bj], acc2[ai][bj], 0, 0, 0);
        }
    }
#pragma unroll
    for (int ai = 0; ai < 4; ++ai)
#pragma unroll
        for (int bj = 0; bj < 4; ++bj) {
            const int colg = col0 + hh * 64 + bj * 16 + l15;
#pragma unroll
            for (int r = 0; r < 4; ++r) {
                const int nl = wn2 + ai * 16 + qd * 4 + r;
                const float v = acc2[ai][bj][r] * zsh[hh * 128 + nl];
                attn[(size_t)(row0 + nl) * KD + colg] = f2b(v);
            }
        }
}

// ---------------------------------------------------------------------------
// out = attn @ Wout + bout. A (bf16) reg-staged with 1-deep prefetch (16 regs),
// B via gl16; counted vmcnt(4) pre-MFMA barrier.
// ---------------------------------------------------------------------------
__global__ __launch_bounds__(256, 4) void gemm_out(const unsigned short* __restrict__ A,
                                                   const unsigned short* __restrict__ BT,
                                                   float* __restrict__ C,
                                                   const float* __restrict__ bias) {
    __shared__ __align__(16) unsigned short buf[17408];
    unsigned short* As = buf;
    unsigned short* Bs = buf + 8192;
    const int tid = threadIdx.x;
    const int lane = tid & 63, wave = tid >> 6;
    const int l15 = lane & 15, qd = lane >> 4;
    const int fid = blockIdx.x;
    const int xcd = fid & 7;
    const int s = fid >> 3;  // 0..95
    const int row0 = (xcd * 32 + s / 3) * 128;
    const int col0 = (s % 3) * 128;
    const int wm = (wave & 1) * 64, wn = (wave >> 1) * 64;

    const unsigned short* Ab = A + (size_t)row0 * KD;
    const unsigned short* Bb = BT + (size_t)col0 * KD;
    const int srow = tid >> 3;
    const int scol = (((tid & 7) ^ (srow & 7)) * 8);

    floatx4 zero = {0.f, 0.f, 0.f, 0.f};
    floatx4 acc[4][4];
#pragma unroll
    for (int i = 0; i < 4; ++i)
#pragma unroll
        for (int j = 0; j < 4; ++j) acc[i][j] = zero;

    const int sw = l15 & 7;
    ushort8v ga[4];
#pragma unroll
    for (int i = 0; i < 4; ++i)  // A(0) prefetch
        ga[i] = *(const ushort8v*)(Ab + (size_t)(i * 32 + srow) * KD + scol);
#pragma unroll
    for (int kk = 0; kk < KD; kk += 64) {
        __syncthreads();
#pragma unroll
        for (int i = 0; i < 4; ++i)
            gl16(Bb + (size_t)(i * 32 + srow) * KD + kk + scol, Bs + i * 2048 + wave * 512);
#pragma unroll
        for (int i = 0; i < 4; ++i)
            *(ushort8v*)&As[i * 2048 + tid * 8] = ga[i];
        if (kk + 64 < KD) {
#pragma unroll
            for (int i = 0; i < 4; ++i)
                ga[i] = *(const ushort8v*)(Ab + (size_t)(i * 32 + srow) * KD + kk + 64 + scol);
            BARRIER_EXEMPT4();
        } else {
            BARRIER_DRAIN();
        }
#pragma unroll
        for (int t = 0; t < 2; ++t) {
            const int chnk = ((t * 4 + qd) ^ sw) * 8;
            short8 af[4], bfr[4];
#pragma unroll
            for (int mi = 0; mi < 4; ++mi)
                af[mi] = *(const short8*)&As[(wm + mi * 16 + l15) * 64 + chnk];
#pragma unroll
            for (int ni = 0; ni < 4; ++ni)
                bfr[ni] = *(const short8*)&Bs[(wn + ni * 16 + l15) * 64 + chnk];
#pragma unroll
            for (int mi = 0; mi < 4; ++mi)
#pragma unroll
                for (int ni = 0; ni < 4; ++ni)
                    acc[mi][ni] = __builtin_amdgcn_mfma_f32_16x16x32_bf16(af[mi], bfr[ni],
                                                                          acc[mi][ni], 0, 0, 0);
        }
    }
#pragma unroll
    for (int mi = 0; mi < 4; ++mi)
#pragma unroll
        for (int ni = 0; ni < 4; ++ni) {
            const int rbase = row0 + wm + mi * 16 + qd * 4;
            const int col = col0 + wn + ni * 16 + l15;
            const float bsv = bias[col];
#pragma unroll
            for (int r = 0; r < 4; ++r)
                __builtin_nontemporal_store(acc[mi][ni][r] + bsv,
                                            &C[(size_t)(rbase + r) * DIMSZ + col]);
        }
}

extern "C" void kernel_launch(void* const* d_in, const int* in_sizes, int n_in,
                              void* d_out, int out_size, void* d_ws, size_t ws_size,
                              hipStream_t stream) {
    const float* x_q = (const float*)d_in[0];
    const float* x_kv = (const float*)d_in[1];
    const float* Wq = (const float*)d_in[2];
    const float* Wkv = (const float*)d_in[3];
    const float* Wout = (const float*)d_in[4];
    const float* bout = (const float*)d_in[5];
    float* out = (float*)d_out;

    char* ws = (char*)d_ws;
    // pkv (25.2 MB, dead after kv_reduce) aliases attn (written later).
    float* pkv = (float*)(ws + 0);                              // 48*32*4096*4 = 25165824
    unsigned short* attn_bf = (unsigned short*)(ws + 0);        // 32768*384*2 = 25165824
    unsigned short* WqT = (unsigned short*)(ws + 25165824);     // 0.29 MB
    unsigned short* WkvT = (unsigned short*)(ws + 25460736);    // 0.59 MB
    unsigned short* WoutT = (unsigned short*)(ws + 26050560);   // 0.29 MB
    float* ksum = (float*)(ws + 26345472);                      // 12 KB
    float* pks = (float*)(ws + 26357760);                       // 0.39 MB
    unsigned short* kv_bf = (unsigned short*)(ws + 26750976);   // 0.39 MB [48][64m][64d]

    dim3 blk(256);
    conv_wt3<<<dim3(48, 12), blk, 0, stream>>>(Wq, Wkv, Wout, WqT, WkvT, WoutT);
    // kv-projection (fp32 A, in-kernel bf16 cvt) fused with kv-state partials
    gemm_kv<<<dim3(1536), blk, 0, stream>>>(x_kv, WkvT, pkv, pks);
    kv_reduce<<<dim3(192), blk, 0, stream>>>(pkv, pks, kv_bf, ksum);
    // q-projection (fp32 A) fused with attention (q never materialized)
    gemm_q_attn<<<dim3(768), blk, 0, stream>>>(x_q, WqT, kv_bf, ksum, attn_bf);
    // out = attn @ Wout + bout
    gemm_out<<<dim3(768), blk, 0, stream>>>(attn_bf, WoutT, out, bout);
}

// Round 6
// 214.835 us; speedup vs baseline: 1.0607x; 1.0607x over previous
//
#include <hip/hip_runtime.h>
#include <math.h>

#define BATCH 8
#define SEQ 4096
#define DIMSZ 384
#define HEADS 6
#define DH 64
#define MTOT (BATCH * SEQ) /* 32768 */
#define KD 384

typedef short short8 __attribute__((ext_vector_type(8)));
typedef float floatx4 __attribute__((ext_vector_type(4)));
typedef unsigned short ushort8v __attribute__((ext_vector_type(8)));
typedef unsigned int uint2v __attribute__((ext_vector_type(2)));
typedef unsigned int uint4v __attribute__((ext_vector_type(4)));

__device__ __forceinline__ float elu1(float x) { return x > 0.f ? x + 1.f : __expf(x); }

__device__ __forceinline__ unsigned short f2b(float f) {
    unsigned int u = __float_as_uint(f);
    u = (u + 0x7fffu + ((u >> 16) & 1u)) >> 16;
    return (unsigned short)u;
}
// packed fp32x2 -> bf16x2 via v_cvt_pk_bf16_f32 (RNE == manual f2b rounding).
__device__ __forceinline__ unsigned int f2b2(float lo, float hi) {
    unsigned int r;
    asm("v_cvt_pk_bf16_f32 %0, %1, %2" : "=v"(r) : "v"(lo), "v"(hi));
    return r;
}

__device__ __forceinline__ void gl16(const void* g, void* l) {
    __builtin_amdgcn_global_load_lds((const __attribute__((address_space(1))) unsigned int*)g,
                                     (__attribute__((address_space(3))) unsigned int*)l, 16, 0, 0);
}

#define SB0() __builtin_amdgcn_sched_barrier(0)
// sync-only barrier: all waves consumed their LDS reads pre-MFMA; no drain.
#define BAR_SOFT()                     \
    do {                               \
        SB0();                         \
        __builtin_amdgcn_s_barrier();  \
        SB0();                         \
    } while (0)
// stage barrier: drain VMEM (gl16 + reg loads, latency already hidden) + LDS writes.
#define BAR_STAGE()                                                 \
    do {                                                            \
        asm volatile("s_waitcnt vmcnt(0) lgkmcnt(0)" ::: "memory"); \
        __builtin_amdgcn_s_barrier();                               \
        SB0();                                                      \
    } while (0)

// ---------------------------------------------------------------------------
// All three weights: W[384][N] fp32 -> WT[N][384] bf16 (transpose + convert).
// ---------------------------------------------------------------------------
__global__ __launch_bounds__(256) void conv_wt3(const float* __restrict__ Wq,
                                                const float* __restrict__ Wkv,
                                                const float* __restrict__ Wout,
                                                unsigned short* __restrict__ WqT,
                                                unsigned short* __restrict__ WkvT,
                                                unsigned short* __restrict__ WoutT) {
    __shared__ float tile[32][33];
    int bx = blockIdx.x;
    const float* W;
    unsigned short* WT;
    int N;
    if (bx < 12) { W = Wq; WT = WqT; N = DIMSZ; }
    else if (bx < 36) { W = Wkv; WT = WkvT; N = 2 * DIMSZ; bx -= 12; }
    else { W = Wout; WT = WoutT; N = DIMSZ; bx -= 36; }
    const int n0 = bx * 32, k0 = blockIdx.y * 32;
    const int tx = threadIdx.x & 31, ty = threadIdx.x >> 5;  // 32 x 8
#pragma unroll
    for (int i = 0; i < 32; i += 8) tile[ty + i][tx] = W[(size_t)(k0 + ty + i) * N + n0 + tx];
    __syncthreads();
#pragma unroll
    for (int i = 0; i < 32; i += 8)
        WT[(size_t)(n0 + ty + i) * KD + k0 + tx] = f2b(tile[tx][ty + i]);
}

// ---------------------------------------------------------------------------
// Fused kv-projection + kv-state partial. 2-PHASE SCHEDULE (R5 post-mortem:
// single-buffer serial chain barrier->stage->drain->MFMA was the 72% idle):
//   B double-buffered (gl16), A single-buffered reg-staged.
//   per K-step: issue B(t+1)->B[nxt] + A(t+1)->regs | MFMA(As,B[cur]) |
//               BAR_SOFT | cvt+ds_write A->As | BAR_STAGE.
// Staging latency (B ~L2 250cy, A ~L2) hides under the MFMA phase.
// LDS 48KB -> 3 blocks/CU.
// ---------------------------------------------------------------------------
__global__ __launch_bounds__(256, 3) void gemm_kv(const float* __restrict__ A,
                                                  const unsigned short* __restrict__ WkvT,
                                                  float* __restrict__ pkv,
                                                  float* __restrict__ pks) {
    __shared__ __align__(16) unsigned short buf[24576];  // As | Bs0 | Bs1 ; epi overlay
    __shared__ float ksLDS[128];
    unsigned short* As = buf;
    unsigned short* Bs0 = buf + 8192;
    unsigned short* Bs1 = buf + 16384;
    const int tid = threadIdx.x;
    const int lane = tid & 63, wave = tid >> 6;
    const int l15 = lane & 15, qd = lane >> 4;
    const int fid = blockIdx.x;
    const int xcd = fid & 7;
    const int s = fid >> 3;          // 0..191
    const int h = s % HEADS;
    const int rtl = s / HEADS;       // 0..31
    const int row0 = (xcd * 32 + rtl) * 128;
    const int pidx = (xcd * HEADS + h) * 32 + rtl;
    const int wm = (wave & 1) * 64, wn = (wave >> 1) * 64;

    const float* Ab = A + (size_t)row0 * KD;
    const unsigned short* Bb = WkvT + (size_t)(h * DH) * KD;  // k rows; v rows at +320*KD bias
    const int srow = tid >> 3;
    const int scol = (((tid & 7) ^ (srow & 7)) * 8);

    floatx4 zero = {0.f, 0.f, 0.f, 0.f};
    floatx4 acc[4][4];
#pragma unroll
    for (int i = 0; i < 4; ++i)
#pragma unroll
        for (int j = 0; j < 4; ++j) acc[i][j] = zero;

    const int sw = l15 & 7;
    float4 g0[4], g1[4];
    // prologue: stage k=0 (serial, once per block)
#pragma unroll
    for (int i = 0; i < 4; ++i)
        gl16(Bb + (size_t)(i * 32 + srow + (i >= 2 ? 320 : 0)) * KD + scol,
             Bs0 + i * 2048 + wave * 512);
#pragma unroll
    for (int i = 0; i < 4; ++i) {
        const float* src = Ab + (size_t)(i * 32 + srow) * KD + scol;
        g0[i] = *(const float4*)src;
        g1[i] = *(const float4*)(src + 4);
    }
#pragma unroll
    for (int i = 0; i < 4; ++i) {
        uint4v u;
        u[0] = f2b2(g0[i].x, g0[i].y);
        u[1] = f2b2(g0[i].z, g0[i].w);
        u[2] = f2b2(g1[i].x, g1[i].y);
        u[3] = f2b2(g1[i].z, g1[i].w);
        *(uint4v*)&As[i * 2048 + tid * 8] = u;
    }
    BAR_STAGE();

#pragma unroll
    for (int t = 0; t < 6; ++t) {
        unsigned short* Bc = (t & 1) ? Bs1 : Bs0;
        if (t < 5) {  // issue next-tile staging BEFORE MFMA (latency hides under it)
            unsigned short* Bn = (t & 1) ? Bs0 : Bs1;
            const int kn = t * 64 + 64;
#pragma unroll
            for (int i = 0; i < 4; ++i)
                gl16(Bb + (size_t)(i * 32 + srow + (i >= 2 ? 320 : 0)) * KD + kn + scol,
                     Bn + i * 2048 + wave * 512);
#pragma unroll
            for (int i = 0; i < 4; ++i) {
                const float* src = Ab + (size_t)(i * 32 + srow) * KD + kn + scol;
                g0[i] = *(const float4*)src;
                g1[i] = *(const float4*)(src + 4);
            }
            SB0();  // pin early issue
        }
#pragma unroll
        for (int tt = 0; tt < 2; ++tt) {
            const int chnk = ((tt * 4 + qd) ^ sw) * 8;
            short8 af[4], bfr[4];
#pragma unroll
            for (int mi = 0; mi < 4; ++mi)
                af[mi] = *(const short8*)&As[(wm + mi * 16 + l15) * 64 + chnk];
#pragma unroll
            for (int ni = 0; ni < 4; ++ni)
                bfr[ni] = *(const short8*)&Bc[(wn + ni * 16 + l15) * 64 + chnk];
#pragma unroll
            for (int mi = 0; mi < 4; ++mi)
#pragma unroll
                for (int ni = 0; ni < 4; ++ni)
                    acc[mi][ni] = __builtin_amdgcn_mfma_f32_16x16x32_bf16(af[mi], bfr[ni],
                                                                          acc[mi][ni], 0, 0, 0);
        }
        if (t < 5) {  // write-late: A(t+1) -> As (all waves done reading A(t))
            BAR_SOFT();
#pragma unroll
            for (int i = 0; i < 4; ++i) {
                uint4v u;
                u[0] = f2b2(g0[i].x, g0[i].y);
                u[1] = f2b2(g0[i].z, g0[i].w);
                u[2] = f2b2(g1[i].x, g1[i].y);
                u[3] = f2b2(g1[i].z, g1[i].w);
                *(uint4v*)&As[i * 2048 + tid * 8] = u;
            }
            BAR_STAGE();
        }
    }

    __syncthreads();  // K-loop LDS reads done before buf reuse
    // transposed bf16 tile buf[c][n] with ksum fused (k-half waves: wn==0)
    const bool kw = (wn == 0);
    float ksp[4] = {};
#pragma unroll
    for (int mi = 0; mi < 4; ++mi)
#pragma unroll
        for (int ni = 0; ni < 4; ++ni) {
            const int rb = wm + mi * 16 + qd * 4;
            const int cl = wn + ni * 16 + l15;
            float v0 = acc[mi][ni][0], v1 = acc[mi][ni][1];
            float v2 = acc[mi][ni][2], v3 = acc[mi][ni][3];
            if (kw) {
                v0 = elu1(v0); v1 = elu1(v1); v2 = elu1(v2); v3 = elu1(v3);
                ksp[ni] += (v0 + v1) + (v2 + v3);
            }
            uint2v o;
            o[0] = f2b2(v0, v1);
            o[1] = f2b2(v2, v3);
            *(uint2v*)&buf[cl * 136 + rb] = o;
        }
    if (kw) {
#pragma unroll
        for (int ni = 0; ni < 4; ++ni) {
            float v = ksp[ni];
            v += __shfl_xor(v, 16);
            v += __shfl_xor(v, 32);
            if (lane < 16) ksLDS[wave * 64 + ni * 16 + lane] = v;
        }
    }
    __syncthreads();
    // kv partial: wave w owns d-strip [w*16, w*16+16); reduce over n=128 (4 ksteps)
    floatx4 kva[4];
#pragma unroll
    for (int j = 0; j < 4; ++j) kva[j] = zero;
#pragma unroll
    for (int nk = 0; nk < 4; ++nk) {
        short8 afk = *(const short8*)&buf[(wave * 16 + l15) * 136 + nk * 32 + qd * 8];
#pragma unroll
        for (int nj = 0; nj < 4; ++nj) {
            short8 bfv = *(const short8*)&buf[(64 + nj * 16 + l15) * 136 + nk * 32 + qd * 8];
            kva[nj] = __builtin_amdgcn_mfma_f32_16x16x32_bf16(afk, bfv, kva[nj], 0, 0, 0);
        }
    }
    // plain stores (not nt): keep partials in L2/L3 for kv_reduce
    float* P = pkv + (size_t)pidx * 4096;
#pragma unroll
    for (int nj = 0; nj < 4; ++nj)
#pragma unroll
        for (int r = 0; r < 4; ++r)
            P[(wave * 16 + qd * 4 + r) * 64 + nj * 16 + l15] = kva[nj][r];
    if (tid < 64) pks[pidx * 64 + tid] = ksLDS[tid] + ksLDS[64 + tid];
}

// ---------------------------------------------------------------------------
// reduce 32 partials per bh -> kv bf16 TRANSPOSED [bh][m][64 d], ksum fp32.
// ---------------------------------------------------------------------------
__global__ __launch_bounds__(256) void kv_reduce(const float* __restrict__ pkv,
                                                 const float* __restrict__ pks,
                                                 unsigned short* __restrict__ kv_bf,
                                                 float* __restrict__ ksum_g) {
    const int bh = blockIdx.x >> 2, dc = blockIdx.x & 3;
    const int tid = threadIdx.x;
    unsigned short* kb = kv_bf + (size_t)bh * 4096;
    const int i0 = dc * 1024 + tid * 4;
    float4 sum = {0.f, 0.f, 0.f, 0.f};
#pragma unroll
    for (int c = 0; c < 32; ++c) {
        float4 p = *(const float4*)&pkv[(size_t)(bh * 32 + c) * 4096 + i0];
        sum.x += p.x; sum.y += p.y; sum.z += p.z; sum.w += p.w;
    }
    const int d = i0 >> 6, m = i0 & 63;  // i0 d-major; 4 consecutive m, same d
    kb[(m + 0) * 64 + d] = f2b(sum.x);
    kb[(m + 1) * 64 + d] = f2b(sum.y);
    kb[(m + 2) * 64 + d] = f2b(sum.z);
    kb[(m + 3) * 64 + d] = f2b(sum.w);
    if (dc == 0 && tid < 64) {
        float s = 0.f;
#pragma unroll
        for (int c = 0; c < 32; ++c) s += pks[(bh * 32 + c) * 64 + tid];
        ksum_g[bh * 64 + tid] = s;
    }
}

// ---------------------------------------------------------------------------
// Fused q-projection + attention (swapped C = q^T). Same 2-phase schedule.
// kv B-fragments direct from global kv_bf (L2-resident) in the epilogue.
// ---------------------------------------------------------------------------
__global__ __launch_bounds__(256, 3) void gemm_q_attn(const float* __restrict__ A,
                                                      const unsigned short* __restrict__ WqT,
                                                      const unsigned short* __restrict__ kv_bf,
                                                      const float* __restrict__ ksum_g,
                                                      unsigned short* __restrict__ attn) {
    __shared__ __align__(16) unsigned short buf[24576];  // As | Bs0 | Bs1 ; q-tile overlay
    __shared__ float ksh[128];
    __shared__ float zsh[256];                           // [2][128]
    unsigned short* As = buf;
    unsigned short* Bs0 = buf + 8192;
    unsigned short* Bs1 = buf + 16384;
    const int tid = threadIdx.x;
    const int lane = tid & 63, wave = tid >> 6;
    const int l15 = lane & 15, qd = lane >> 4;
    const int fid = blockIdx.x;
    const int xcd = fid & 7;
    const int s = fid >> 3;          // 0..95
    const int ct = s % 3;
    const int rtl = s / 3;
    const int row0 = (xcd * 32 + rtl) * 128;
    const int col0 = ct * 128;
    const int bh0 = xcd * HEADS + ct * 2;
    const int wd = (wave & 1) * 64, wn2 = (wave >> 1) * 64;

    if (tid < 128) ksh[tid] = ksum_g[bh0 * 64 + tid];

    const float* Ab = A + (size_t)row0 * KD;
    const unsigned short* Bb = WqT + (size_t)col0 * KD;
    const int srow = tid >> 3;
    const int scol = (((tid & 7) ^ (srow & 7)) * 8);

    floatx4 zero = {0.f, 0.f, 0.f, 0.f};
    floatx4 acc[4][4];
#pragma unroll
    for (int i = 0; i < 4; ++i)
#pragma unroll
        for (int j = 0; j < 4; ++j) acc[i][j] = zero;

    const int sw = l15 & 7;
    float4 g0[4], g1[4];
#pragma unroll
    for (int i = 0; i < 4; ++i)
        gl16(Bb + (size_t)(i * 32 + srow) * KD + scol, Bs0 + i * 2048 + wave * 512);
#pragma unroll
    for (int i = 0; i < 4; ++i) {
        const float* src = Ab + (size_t)(i * 32 + srow) * KD + scol;
        g0[i] = *(const float4*)src;
        g1[i] = *(const float4*)(src + 4);
    }
#pragma unroll
    for (int i = 0; i < 4; ++i) {
        uint4v u;
        u[0] = f2b2(g0[i].x, g0[i].y);
        u[1] = f2b2(g0[i].z, g0[i].w);
        u[2] = f2b2(g1[i].x, g1[i].y);
        u[3] = f2b2(g1[i].z, g1[i].w);
        *(uint4v*)&As[i * 2048 + tid * 8] = u;
    }
    BAR_STAGE();

#pragma unroll
    for (int t = 0; t < 6; ++t) {
        unsigned short* Bc = (t & 1) ? Bs1 : Bs0;
        if (t < 5) {
            unsigned short* Bn = (t & 1) ? Bs0 : Bs1;
            const int kn = t * 64 + 64;
#pragma unroll
            for (int i = 0; i < 4; ++i)
                gl16(Bb + (size_t)(i * 32 + srow) * KD + kn + scol, Bn + i * 2048 + wave * 512);
#pragma unroll
            for (int i = 0; i < 4; ++i) {
                const float* src = Ab + (size_t)(i * 32 + srow) * KD + kn + scol;
                g0[i] = *(const float4*)src;
                g1[i] = *(const float4*)(src + 4);
            }
            SB0();
        }
#pragma unroll
        for (int tt = 0; tt < 2; ++tt) {
            const int chnk = ((tt * 4 + qd) ^ sw) * 8;
            short8 wf[4], xf[4];
#pragma unroll
            for (int di = 0; di < 4; ++di)
                wf[di] = *(const short8*)&Bc[(wd + di * 16 + l15) * 64 + chnk];
#pragma unroll
            for (int nj = 0; nj < 4; ++nj)
                xf[nj] = *(const short8*)&As[(wn2 + nj * 16 + l15) * 64 + chnk];
#pragma unroll
            for (int di = 0; di < 4; ++di)
#pragma unroll
                for (int nj = 0; nj < 4; ++nj)  // swapped: C[d][n]
                    acc[di][nj] = __builtin_amdgcn_mfma_f32_16x16x32_bf16(wf[di], xf[nj],
                                                                          acc[di][nj], 0, 0, 0);
        }
        if (t < 5) {
            BAR_SOFT();
#pragma unroll
            for (int i = 0; i < 4; ++i) {
                uint4v u;
                u[0] = f2b2(g0[i].x, g0[i].y);
                u[1] = f2b2(g0[i].z, g0[i].w);
                u[2] = f2b2(g1[i].x, g1[i].y);
                u[3] = f2b2(g1[i].z, g1[i].w);
                *(uint4v*)&As[i * 2048 + tid * 8] = u;
            }
            BAR_STAGE();
        }
    }

    // elu + z partials: this wave's d-range = one full head (wd selects head)
    float zp[4] = {};
#pragma unroll
    for (int di = 0; di < 4; ++di)
#pragma unroll
        for (int r = 0; r < 4; ++r) {
            const float ks = ksh[wd + di * 16 + qd * 4 + r];
#pragma unroll
            for (int nj = 0; nj < 4; ++nj) {
                const float q = elu1(acc[di][nj][r]);
                acc[di][nj][r] = q;
                zp[nj] += q * ks;
            }
        }
#pragma unroll
    for (int nj = 0; nj < 4; ++nj) {
        float v = zp[nj];
        v += __shfl_xor(v, 16);
        v += __shfl_xor(v, 32);
        zp[nj] = 1.f / (v + 1e-6f);
    }
    __syncthreads();  // K-loop LDS reads done before buf reuse
    if (lane < 16) {
#pragma unroll
        for (int nj = 0; nj < 4; ++nj) zsh[(wave & 1) * 128 + wn2 + nj * 16 + lane] = zp[nj];
    }
    // transposed write -> q ROW-MAJOR in LDS: buf[n][d], stride 136
#pragma unroll
    for (int di = 0; di < 4; ++di)
#pragma unroll
        for (int nj = 0; nj < 4; ++nj) {
            const int rb = wd + di * 16 + qd * 4;    // d
            const int cl = wn2 + nj * 16 + l15;      // n
            uint2v o;
            o[0] = f2b2(acc[di][nj][0], acc[di][nj][1]);
            o[1] = f2b2(acc[di][nj][2], acc[di][nj][3]);
            *(uint2v*)&buf[cl * 136 + rb] = o;
        }
    __syncthreads();
    // attn quadrant: n in [wn2,wn2+64), head hh = wave&1, K = 64 d (2 ksteps)
    const int hh = wave & 1;
    const unsigned short* kvB = kv_bf + (size_t)(bh0 + hh) * 4096;
    floatx4 acc2[4][4];
#pragma unroll
    for (int i = 0; i < 4; ++i)
#pragma unroll
        for (int j = 0; j < 4; ++j) acc2[i][j] = zero;
#pragma unroll
    for (int t = 0; t < 2; ++t) {
        short8 bf2[4];
#pragma unroll
        for (int bj = 0; bj < 4; ++bj)
            bf2[bj] = *(const short8*)&kvB[(bj * 16 + l15) * 64 + t * 32 + qd * 8];
#pragma unroll
        for (int ai = 0; ai < 4; ++ai) {
            short8 af =
                *(const short8*)&buf[(wn2 + ai * 16 + l15) * 136 + hh * 64 + t * 32 + qd * 8];
#pragma unroll
            for (int bj = 0; bj < 4; ++bj)
                acc2[ai][bj] =
                    __builtin_amdgcn_mfma_f32_16x16x32_bf16(af, bf2[bj], acc2[ai][bj], 0, 0, 0);
        }
    }
#pragma unroll
    for (int ai = 0; ai < 4; ++ai)
#pragma unroll
        for (int bj = 0; bj < 4; ++bj) {
            const int colg = col0 + hh * 64 + bj * 16 + l15;
#pragma unroll
            for (int r = 0; r < 4; ++r) {
                const int nl = wn2 + ai * 16 + qd * 4 + r;
                const float v = acc2[ai][bj][r] * zsh[hh * 128 + nl];
                attn[(size_t)(row0 + nl) * KD + colg] = f2b(v);
            }
        }
}

// ---------------------------------------------------------------------------
// out = attn @ Wout + bout. Same 2-phase schedule; A bf16 reg-staged (no cvt).
// ---------------------------------------------------------------------------
__global__ __launch_bounds__(256, 3) void gemm_out(const unsigned short* __restrict__ A,
                                                   const unsigned short* __restrict__ BT,
                                                   float* __restrict__ C,
                                                   const float* __restrict__ bias) {
    __shared__ __align__(16) unsigned short buf[24576];  // As | Bs0 | Bs1
    unsigned short* As = buf;
    unsigned short* Bs0 = buf + 8192;
    unsigned short* Bs1 = buf + 16384;
    const int tid = threadIdx.x;
    const int lane = tid & 63, wave = tid >> 6;
    const int l15 = lane & 15, qd = lane >> 4;
    const int fid = blockIdx.x;
    const int xcd = fid & 7;
    const int s = fid >> 3;  // 0..95
    const int row0 = (xcd * 32 + s / 3) * 128;
    const int col0 = (s % 3) * 128;
    const int wm = (wave & 1) * 64, wn = (wave >> 1) * 64;

    const unsigned short* Ab = A + (size_t)row0 * KD;
    const unsigned short* Bb = BT + (size_t)col0 * KD;
    const int srow = tid >> 3;
    const int scol = (((tid & 7) ^ (srow & 7)) * 8);

    floatx4 zero = {0.f, 0.f, 0.f, 0.f};
    floatx4 acc[4][4];
#pragma unroll
    for (int i = 0; i < 4; ++i)
#pragma unroll
        for (int j = 0; j < 4; ++j) acc[i][j] = zero;

    const int sw = l15 & 7;
    ushort8v ga[4];
#pragma unroll
    for (int i = 0; i < 4; ++i)
        gl16(Bb + (size_t)(i * 32 + srow) * KD + scol, Bs0 + i * 2048 + wave * 512);
#pragma unroll
    for (int i = 0; i < 4; ++i)
        ga[i] = *(const ushort8v*)(Ab + (size_t)(i * 32 + srow) * KD + scol);
#pragma unroll
    for (int i = 0; i < 4; ++i) *(ushort8v*)&As[i * 2048 + tid * 8] = ga[i];
    BAR_STAGE();

#pragma unroll
    for (int t = 0; t < 6; ++t) {
        unsigned short* Bc = (t & 1) ? Bs1 : Bs0;
        if (t < 5) {
            unsigned short* Bn = (t & 1) ? Bs0 : Bs1;
            const int kn = t * 64 + 64;
#pragma unroll
            for (int i = 0; i < 4; ++i)
                gl16(Bb + (size_t)(i * 32 + srow) * KD + kn + scol, Bn + i * 2048 + wave * 512);
#pragma unroll
            for (int i = 0; i < 4; ++i)
                ga[i] = *(const ushort8v*)(Ab + (size_t)(i * 32 + srow) * KD + kn + scol);
            SB0();
        }
#pragma unroll
        for (int tt = 0; tt < 2; ++tt) {
            const int chnk = ((tt * 4 + qd) ^ sw) * 8;
            short8 af[4], bfr[4];
#pragma unroll
            for (int mi = 0; mi < 4; ++mi)
                af[mi] = *(const short8*)&As[(wm + mi * 16 + l15) * 64 + chnk];
#pragma unroll
            for (int ni = 0; ni < 4; ++ni)
                bfr[ni] = *(const short8*)&Bc[(wn + ni * 16 + l15) * 64 + chnk];
#pragma unroll
            for (int mi = 0; mi < 4; ++mi)
#pragma unroll
                for (int ni = 0; ni < 4; ++ni)
                    acc[mi][ni] = __builtin_amdgcn_mfma_f32_16x16x32_bf16(af[mi], bfr[ni],
                                                                          acc[mi][ni], 0, 0, 0);
        }
        if (t < 5) {
            BAR_SOFT();
#pragma unroll
            for (int i = 0; i < 4; ++i) *(ushort8v*)&As[i * 2048 + tid * 8] = ga[i];
            BAR_STAGE();
        }
    }
#pragma unroll
    for (int mi = 0; mi < 4; ++mi)
#pragma unroll
        for (int ni = 0; ni < 4; ++ni) {
            const int rbase = row0 + wm + mi * 16 + qd * 4;
            const int col = col0 + wn + ni * 16 + l15;
            const float bsv = bias[col];
#pragma unroll
            for (int r = 0; r < 4; ++r)
                __builtin_nontemporal_store(acc[mi][ni][r] + bsv,
                                            &C[(size_t)(rbase + r) * DIMSZ + col]);
        }
}

extern "C" void kernel_launch(void* const* d_in, const int* in_sizes, int n_in,
                              void* d_out, int out_size, void* d_ws, size_t ws_size,
                              hipStream_t stream) {
    const float* x_q = (const float*)d_in[0];
    const float* x_kv = (const float*)d_in[1];
    const float* Wq = (const float*)d_in[2];
    const float* Wkv = (const float*)d_in[3];
    const float* Wout = (const float*)d_in[4];
    const float* bout = (const float*)d_in[5];
    float* out = (float*)d_out;

    char* ws = (char*)d_ws;
    // pkv (25.2 MB, dead after kv_reduce) aliases attn (written later).
    float* pkv = (float*)(ws + 0);                              // 48*32*4096*4 = 25165824
    unsigned short* attn_bf = (unsigned short*)(ws + 0);        // 32768*384*2 = 25165824
    unsigned short* WqT = (unsigned short*)(ws + 25165824);     // 0.29 MB
    unsigned short* WkvT = (unsigned short*)(ws + 25460736);    // 0.59 MB
    unsigned short* WoutT = (unsigned short*)(ws + 26050560);   // 0.29 MB
    float* ksum = (float*)(ws + 26345472);                      // 12 KB
    float* pks = (float*)(ws + 26357760);                       // 0.39 MB
    unsigned short* kv_bf = (unsigned short*)(ws + 26750976);   // 0.39 MB [48][64m][64d]

    dim3 blk(256);
    conv_wt3<<<dim3(48, 12), blk, 0, stream>>>(Wq, Wkv, Wout, WqT, WkvT, WoutT);
    // kv-projection (fp32 A, in-kernel bf16 cvt) fused with kv-state partials
    gemm_kv<<<dim3(1536), blk, 0, stream>>>(x_kv, WkvT, pkv, pks);
    kv_reduce<<<dim3(192), blk, 0, stream>>>(pkv, pks, kv_bf, ksum);
    // q-projection (fp32 A) fused with attention (q never materialized)
    gemm_q_attn<<<dim3(768), blk, 0, stream>>>(x_q, WqT, kv_bf, ksum, attn_bf);
    // out = attn @ Wout + bout
    gemm_out<<<dim3(768), blk, 0, stream>>>(attn_bf, WoutT, out, bout);
}